// Round 7
// baseline (150.272 us; speedup 1.0000x reference)
//
#include <hip/hip_runtime.h>

#define DIM 1024
#define HEADS 16
#define HD 64
#define BATCH 2
#define SEQ 2048
#define ROWS (BATCH*SEQ)          // 4096
#define EPS 1e-6f

typedef float f32x4  __attribute__((ext_vector_type(4)));
typedef float f32x16 __attribute__((ext_vector_type(16)));
typedef short s16x4  __attribute__((ext_vector_type(4)));
typedef short s16x8  __attribute__((ext_vector_type(8)));

static __device__ __forceinline__ short f2bf(float f) {
    union { float f; unsigned u; } x; x.f = f;
    unsigned r = x.u + 0x7FFFu + ((x.u >> 16) & 1u);
    return (short)(r >> 16);
}
static __device__ __forceinline__ s16x8 pack8(float4 lo, float4 hi) {
    s16x8 r;
    r[0]=f2bf(lo.x); r[1]=f2bf(lo.y); r[2]=f2bf(lo.z); r[3]=f2bf(lo.w);
    r[4]=f2bf(hi.x); r[5]=f2bf(hi.y); r[6]=f2bf(hi.z); r[7]=f2bf(hi.w);
    return r;
}
static __device__ __forceinline__ unsigned cvtpk(float a, float b) {
    unsigned r;
    asm("v_cvt_pk_bf16_f32 %0, %1, %2" : "=v"(r) : "v"(a), "v"(b));
    return r;
}
static __device__ __forceinline__ void gld16(short* l, const short* g) {
    __builtin_amdgcn_global_load_lds(
        (const __attribute__((address_space(1))) void*)g,
        (__attribute__((address_space(3))) void*)l, 16, 0, 0);
}

#define MFMA32(A,B,C) __builtin_amdgcn_mfma_f32_32x32x16_bf16(A, B, C, 0, 0, 0)
#define MFMA16(A,B,C) __builtin_amdgcn_mfma_f32_16x16x32_bf16(A, B, C, 0, 0, 0)

// ---------------------------------------------------------------------------
// fp32 -> bf16 conversion for x, W_qkv, W_proj (one pass, vectorized)
// ---------------------------------------------------------------------------
__global__ __launch_bounds__(256) void convert3(
    const float* __restrict__ x, const float* __restrict__ wq,
    const float* __restrict__ wp,
    short* __restrict__ xb, short* __restrict__ wqb, short* __restrict__ wpb)
{
    const int idx = blockIdx.x * 256 + threadIdx.x;   // one 8-elem chunk
    const int C1 = 4194304/8, C2 = 3145728/8;
    const float* src; short* dst; int off;
    if (idx < C1)            { src = x;  dst = xb;  off = idx; }
    else if (idx < C1 + C2)  { src = wq; dst = wqb; off = idx - C1; }
    else                     { src = wp; dst = wpb; off = idx - C1 - C2; }
    float4 a = ((const float4*)src)[off*2];
    float4 b = ((const float4*)src)[off*2 + 1];
    ((s16x8*)dst)[off] = pack8(a, b);
}

// ---------------------------------------------------------------------------
// bf16 GEMM, m97 structure: 128x128 tile, BK=64, global_load_lds staging.
// MODE 0: fused per-head LayerNorm on q/k, scatter bf16 q/k/v to [B,H,N,D]
// MODE 1: bias add, fp32 out
// ---------------------------------------------------------------------------
#define BKG 64

template<int MODE>
__global__ __launch_bounds__(256) void gemm_bf16(
    const short* __restrict__ A, const short* __restrict__ W,
    const float* __restrict__ bias,
    const float* __restrict__ qg, const float* __restrict__ qbeta,
    const float* __restrict__ kg, const float* __restrict__ kbeta,
    short* __restrict__ qb, short* __restrict__ kb, short* __restrict__ vb,
    float* __restrict__ out)
{
    alignas(16) __shared__ short As[128*BKG];
    alignas(16) __shared__ short Bs[128*BKG];
    const int tid  = threadIdx.x;
    const int lane = tid & 63, wave = tid >> 6;
    const int wr = wave >> 1, wc = wave & 1;
    const int c = lane & 15, g = lane >> 4;
    const int brow = blockIdx.y * 128, bcol = blockIdx.x * 128;

    const int srow = lane >> 3;
    const int scol = (lane & 7) * 8;
    const short* ag = A + (size_t)(brow + srow)*DIM + scol;
    const short* wg = W + (size_t)(bcol + srow)*DIM + scol;

    f32x4 acc[4][4] = {};

    for (int k0 = 0; k0 < DIM; k0 += BKG) {
        #pragma unroll
        for (int j = 0; j < 4; j++) {
            const int rg = (wave*4 + j) * 8;
            gld16(&As[rg*BKG], ag + (size_t)rg*DIM + k0);
            gld16(&Bs[rg*BKG], wg + (size_t)rg*DIM + k0);
        }
        __syncthreads();

        #pragma unroll
        for (int ks = 0; ks < 2; ks++) {
            s16x8 af[4], bf[4];
            #pragma unroll
            for (int m = 0; m < 4; m++)
                af[m] = *(const s16x8*)&As[(wr*64 + m*16 + c)*BKG + ks*32 + g*8];
            #pragma unroll
            for (int n = 0; n < 4; n++)
                bf[n] = *(const s16x8*)&Bs[(wc*64 + n*16 + c)*BKG + ks*32 + g*8];
            #pragma unroll
            for (int m = 0; m < 4; m++)
                #pragma unroll
                for (int n = 0; n < 4; n++)
                    acc[m][n] = MFMA16(af[m], bf[n], acc[m][n]);
        }
        __syncthreads();
    }

    if (MODE == 0) {
        const int colbase = bcol + wc*64;
        const int t = colbase >> 10;               // 0:q 1:k 2:v
        const int h = (colbase >> 6) & 15;
        short* dst = (t == 0) ? qb : (t == 1) ? kb : vb;
        float gam[4], bet[4];
        float scale = 1.0f;
        if (t < 2) {
            const float* G  = (t == 0) ? qg : kg;
            const float* Bt = (t == 0) ? qbeta : kbeta;
            #pragma unroll
            for (int n = 0; n < 4; n++) { gam[n] = G[n*16 + c]; bet[n] = Bt[n*16 + c]; }
            if (t == 0) scale = 0.125f * 1.44269504088896340736f;  // D^-0.5 * log2e
        }
        #pragma unroll
        for (int m = 0; m < 4; m++) {
            #pragma unroll
            for (int j = 0; j < 4; j++) {
                const int row = brow + wr*64 + m*16 + g*4 + j;
                const int bi = row >> 11, ni = row & (SEQ-1);
                const size_t rb = ((size_t)(bi*HEADS + h)*SEQ + ni)*HD;
                float v0 = acc[m][0][j], v1 = acc[m][1][j];
                float v2 = acc[m][2][j], v3 = acc[m][3][j];
                if (t < 2) {
                    float s = (v0 + v1) + (v2 + v3);
                    s += __shfl_xor(s, 1); s += __shfl_xor(s, 2);
                    s += __shfl_xor(s, 4); s += __shfl_xor(s, 8);
                    const float mu = s * 0.015625f;
                    v0 -= mu; v1 -= mu; v2 -= mu; v3 -= mu;
                    float vv = (v0*v0 + v1*v1) + (v2*v2 + v3*v3);
                    vv += __shfl_xor(vv, 1); vv += __shfl_xor(vv, 2);
                    vv += __shfl_xor(vv, 4); vv += __shfl_xor(vv, 8);
                    const float rstd = rsqrtf(vv * 0.015625f + EPS);
                    v0 = (v0*rstd*gam[0] + bet[0]) * scale;
                    v1 = (v1*rstd*gam[1] + bet[1]) * scale;
                    v2 = (v2*rstd*gam[2] + bet[2]) * scale;
                    v3 = (v3*rstd*gam[3] + bet[3]) * scale;
                }
                dst[rb + 0*16 + c] = f2bf(v0);
                dst[rb + 1*16 + c] = f2bf(v1);
                dst[rb + 2*16 + c] = f2bf(v2);
                dst[rb + 3*16 + c] = f2bf(v3);
            }
        }
    } else {
        #pragma unroll
        for (int n = 0; n < 4; n++) {
            const int col = bcol + wc*64 + n*16 + c;
            const float bv = bias[col];
            #pragma unroll
            for (int m = 0; m < 4; m++) {
                #pragma unroll
                for (int j = 0; j < 4; j++) {
                    const int row = brow + wr*64 + m*16 + g*4 + j;
                    out[(size_t)row*DIM + col] = acc[m][n][j] + bv;
                }
            }
        }
    }
}

// ---------------------------------------------------------------------------
// Repack K,V into MFMA-fragment order so attn loads are lane-coalesced:
//  KP[bh][tile32][ks(0..3)][lane][e] = K[bh][tile*32+(lane&31)][ks*16+8*(lane>>5)+e]
//  VP[bh][tile32][idx(0..3)][lane][e] = V[bh][tile*32+(idx>>1)*16+8*(lane>>5)+e][(idx&1)*32+(lane&31)]
// One block handles 64 keys (2 tiles) of one bh.
// ---------------------------------------------------------------------------
__global__ __launch_bounds__(256) void repack_kv(
    const short* __restrict__ kin, const short* __restrict__ vin,
    short* __restrict__ KP, short* __restrict__ VP)
{
    constexpr int LT = 72;
    alignas(16) __shared__ short Kl[64*LT];
    alignas(16) __shared__ short Vl[64*LT];
    const int bh = blockIdx.x, n0 = blockIdx.y * 64;
    const int tid = threadIdx.x;
    const int r = tid >> 2, cq = (tid & 3) * 16;
    {
        const short* ksrc = kin + ((size_t)bh*SEQ + n0 + r)*HD + cq;
        const short* vsrc = vin + ((size_t)bh*SEQ + n0 + r)*HD + cq;
        *(s16x8*)&Kl[r*LT + cq]     = *(const s16x8*)ksrc;
        *(s16x8*)&Kl[r*LT + cq + 8] = *(const s16x8*)(ksrc + 8);
        *(s16x8*)&Vl[r*LT + cq]     = *(const s16x8*)vsrc;
        *(s16x8*)&Vl[r*LT + cq + 8] = *(const s16x8*)(vsrc + 8);
    }
    __syncthreads();
    const int tt = tid >> 7;              // tile 0/1
    const int r2 = tid & 127;
    const int sub = r2 >> 5, lp = r2 & 31;
    const size_t tbase = ((size_t)bh*64 + blockIdx.y*2 + tt)*2048 + sub*512;
    // K granules
    #pragma unroll
    for (int g2 = 0; g2 < 2; g2++) {
        const int lane = 2*lp + g2;
        s16x8 val = *(const s16x8*)&Kl[(tt*32 + (lane & 31))*LT + sub*16 + 8*(lane >> 5)];
        *(s16x8*)&KP[tbase + lane*8] = val;
    }
    // V granules (idx = sub): ks2 = sub>>1, ch = sub&1
    #pragma unroll
    for (int g2 = 0; g2 < 2; g2++) {
        const int lane = 2*lp + g2;
        const int hi = lane >> 5, l31 = lane & 31;
        s16x8 val;
        #pragma unroll
        for (int e = 0; e < 8; e++)
            val[e] = Vl[(tt*32 + (sub >> 1)*16 + 8*hi + e)*LT + (sub & 1)*32 + l31];
        *(s16x8*)&VP[tbase + lane*8] = val;
    }
}

// ---------------------------------------------------------------------------
// Flash attention, barrier-free: fragment-packed K/V in global (coalesced
// per-lane loads, L1/L2-resident), KVBLK=32, split-K 2 halves x 2 q-subtiles
// per 256-thread block, single end-of-kernel merge through LDS.
// ---------------------------------------------------------------------------
__global__ __launch_bounds__(256) void attn_kernel(
    const short* __restrict__ qbuf, const short* __restrict__ KP,
    const short* __restrict__ VP, short* __restrict__ aout)
{
    alignas(16) __shared__ float OL[2][64][32];   // [qsub][lane][reg]
    __shared__ float ML[2][2][64];                // [qsub][{m,l}][lane]

    const int bh = blockIdx.x, qt = blockIdx.y;
    const int tid = threadIdx.x, wave = tid >> 6, lane = tid & 63;
    const int qsub = wave >> 1, half = wave & 1;
    const int l31 = lane & 31, hi = lane >> 5;
    const int q0 = qt*64 + qsub*32;

    s16x8 qf[4];
    const short* qrow = qbuf + ((size_t)bh*SEQ + q0 + l31)*HD + 8*hi;
    #pragma unroll
    for (int ks = 0; ks < 4; ks++) qf[ks] = *(const s16x8*)(qrow + 16*ks);

    const short* kp = KP + ((size_t)bh*64 + half*32)*2048 + lane*8;
    const short* vp = VP + ((size_t)bh*64 + half*32)*2048 + lane*8;

    f32x16 o0 = {}, o1 = {};
    float m = -1e30f, l = 0.f;

    for (int it = 0; it < 32; it++) {
        // coalesced fragment loads: K first (used now), V second (used after softmax)
        s16x8 kc0 = *(const s16x8*)(kp);
        s16x8 kc1 = *(const s16x8*)(kp + 512);
        s16x8 kc2 = *(const s16x8*)(kp + 1024);
        s16x8 kc3 = *(const s16x8*)(kp + 1536);
        s16x8 vc0 = *(const s16x8*)(vp);
        s16x8 vc1 = *(const s16x8*)(vp + 512);
        s16x8 vc2 = *(const s16x8*)(vp + 1024);
        s16x8 vc3 = *(const s16x8*)(vp + 1536);
        kp += 2048; vp += 2048;
        __builtin_amdgcn_sched_barrier(0);

        // S^T = K*Q : lane holds 16 keys for q = q0+l31
        f32x16 s = {};
        __builtin_amdgcn_s_setprio(1);
        s = MFMA32(kc0, qf[0], s);
        s = MFMA32(kc1, qf[1], s);
        s = MFMA32(kc2, qf[2], s);
        s = MFMA32(kc3, qf[3], s);
        __builtin_amdgcn_s_setprio(0);

        // softmax
        float t8[8];
        #pragma unroll
        for (int i = 0; i < 8; i++) t8[i] = fmaxf(s[i], s[i+8]);
        #pragma unroll
        for (int i = 0; i < 4; i++) t8[i] = fmaxf(t8[i], t8[i+4]);
        float pmax = fmaxf(fmaxf(t8[0], t8[2]), fmaxf(t8[1], t8[3]));
        pmax = fmaxf(pmax, __shfl_xor(pmax, 32));

        if (!__all(pmax - m <= 8.0f)) {           // defer-max (T13)
            float mn = fmaxf(m, pmax);
            float corr = exp2f(m - mn);
            #pragma unroll
            for (int i = 0; i < 16; i++) { o0[i] *= corr; o1[i] *= corr; }
            l *= corr;
            m = mn;
        }
        #pragma unroll
        for (int i = 0; i < 16; i++) s[i] = exp2f(s[i] - m);
        float a8[8];
        #pragma unroll
        for (int i = 0; i < 8; i++) a8[i] = s[i] + s[i+8];
        #pragma unroll
        for (int i = 0; i < 4; i++) a8[i] += a8[i+4];
        float rs = (a8[0] + a8[2]) + (a8[1] + a8[3]);
        rs += __shfl_xor(rs, 32);
        l += rs;

        // P -> bf16 B-fragments via cvt_pk + permlane32_swap (T12)
        s16x8 pa0, pa1;
        {
            unsigned A0 = cvtpk(s[0], s[1]),  A1 = cvtpk(s[2], s[3]);
            unsigned B0 = cvtpk(s[4], s[5]),  B1 = cvtpk(s[6], s[7]);
            asm volatile("v_permlane32_swap_b32 %0, %1" : "+v"(A0), "+v"(B0));
            asm volatile("v_permlane32_swap_b32 %0, %1" : "+v"(A1), "+v"(B1));
            union { s16x8 v; unsigned u[4]; } w;
            w.u[0]=A0; w.u[1]=A1; w.u[2]=B0; w.u[3]=B1;
            pa0 = w.v;
            unsigned C0 = cvtpk(s[8], s[9]),  C1 = cvtpk(s[10], s[11]);
            unsigned D0 = cvtpk(s[12], s[13]),D1 = cvtpk(s[14], s[15]);
            asm volatile("v_permlane32_swap_b32 %0, %1" : "+v"(C0), "+v"(D0));
            asm volatile("v_permlane32_swap_b32 %0, %1" : "+v"(C1), "+v"(D1));
            union { s16x8 v; unsigned u[4]; } w2;
            w2.u[0]=C0; w2.u[1]=C1; w2.u[2]=D0; w2.u[3]=D1;
            pa1 = w2.v;
        }

        // O^T += V^T * P
        __builtin_amdgcn_s_setprio(1);
        o0 = MFMA32(vc0, pa0, o0);
        o1 = MFMA32(vc1, pa0, o1);
        o0 = MFMA32(vc2, pa1, o0);
        o1 = MFMA32(vc3, pa1, o1);
        __builtin_amdgcn_s_setprio(0);
    }

    // ---- merge the two K-halves ----
    if (half == 1) {
        float* ob = &OL[qsub][lane][0];
        #pragma unroll
        for (int i = 0; i < 8; i++) {
            const int slot = (i + (lane & 7)) & 7;
            f32x4 v;
            if (i < 4) { v[0]=o0[4*i]; v[1]=o0[4*i+1]; v[2]=o0[4*i+2]; v[3]=o0[4*i+3]; }
            else { const int j = i-4; v[0]=o1[4*j]; v[1]=o1[4*j+1]; v[2]=o1[4*j+2]; v[3]=o1[4*j+3]; }
            *(f32x4*)(ob + slot*4) = v;
        }
        ML[qsub][0][lane] = m;
        ML[qsub][1][lane] = l;
    }
    __syncthreads();
    if (half == 0) {
        const float m1 = ML[qsub][0][lane];
        const float l1 = ML[qsub][1][lane];
        const float ms = fmaxf(m, m1);
        const float c0 = exp2f(m - ms), c1 = exp2f(m1 - ms);
        const float inv = 1.0f / (l*c0 + l1*c1);
        const float* ob = &OL[qsub][lane][0];
        const int b = bh >> 4, h = bh & 15;
        short* dst = aout + ((size_t)(b*SEQ + q0 + l31))*DIM + h*HD;
        #pragma unroll
        for (int i = 0; i < 8; i++) {
            const int slot = (i + (lane & 7)) & 7;
            f32x4 p = *(const f32x4*)(ob + slot*4);
            s16x4 st;
            if (i < 4) {
                #pragma unroll
                for (int j = 0; j < 4; j++) st[j] = f2bf((o0[4*i+j]*c0 + p[j]*c1) * inv);
                *(s16x4*)(dst + 8*i + 4*hi) = st;
            } else {
                const int t3 = i - 4;
                #pragma unroll
                for (int j = 0; j < 4; j++) st[j] = f2bf((o1[4*t3+j]*c0 + p[j]*c1) * inv);
                *(s16x4*)(dst + 32 + 8*t3 + 4*hi) = st;
            }
        }
    }
}

// ---------------------------------------------------------------------------
extern "C" void kernel_launch(void* const* d_in, const int* in_sizes, int n_in,
                              void* d_out, int out_size, void* d_ws, size_t ws_size,
                              hipStream_t stream)
{
    const float* x     = (const float*)d_in[0];
    const float* Wqkv  = (const float*)d_in[1];
    const float* qg    = (const float*)d_in[2];
    const float* qbeta = (const float*)d_in[3];
    const float* kg    = (const float*)d_in[4];
    const float* kbeta = (const float*)d_in[5];
    const float* Wproj = (const float*)d_in[6];
    const float* bproj = (const float*)d_in[7];
    float* out = (float*)d_out;

    char* ws = (char*)d_ws;
    const size_t MB = 1024*1024;
    short* xb     = (short*)(ws);              // 8 MB; dead after gemm<0>
    short* KP     = (short*)(ws);              // reuses xb slot (written by repack)
    short* wqkvb  = (short*)(ws + 8*MB);       // 6 MB
    short* wprojb = (short*)(ws + 14*MB);      // 2 MB (live until gemm<1>)
    short* q      = (short*)(ws + 16*MB);      // 8 MB
    short* k      = (short*)(ws + 24*MB);      // 8 MB; dead after repack
    short* aout   = (short*)(ws + 24*MB);      // reuses k slot (written by attn)
    short* vrow   = (short*)(ws + 32*MB);      // 8 MB; dead after repack
    short* VP     = (short*)(ws + 40*MB);      // 8 MB

    // 1. fp32 -> bf16 conversions
    convert3<<<dim3(4096), 256, 0, stream>>>(x, Wqkv, Wproj, xb, wqkvb, wprojb);

    // 2. QKV GEMM + fused q/k LayerNorm, scatter
    gemm_bf16<0><<<dim3(3*DIM/128, ROWS/128), 256, 0, stream>>>(
        xb, wqkvb, nullptr, qg, qbeta, kg, kbeta, q, k, vrow, nullptr);

    // 3. Repack K,V into fragment order
    repack_kv<<<dim3(BATCH*HEADS, SEQ/64), 256, 0, stream>>>(k, vrow, KP, VP);

    // 4. Flash attention (barrier-free, split-K, bf16 out)
    attn_kernel<<<dim3(BATCH*HEADS, SEQ/64), 256, 0, stream>>>(q, KP, VP, aout);

    // 5. Projection GEMM + bias -> fp32 d_out
    gemm_bf16<1><<<dim3(DIM/128, ROWS/128), 256, 0, stream>>>(
        aout, wprojb, bproj, nullptr, nullptr, nullptr, nullptr,
        nullptr, nullptr, nullptr, out);
}

// Round 9
// 147.559 us; speedup vs baseline: 1.0184x; 1.0184x over previous
//
#include <hip/hip_runtime.h>

#define DIM 1024
#define HEADS 16
#define HD 64
#define BATCH 2
#define SEQ 2048
#define ROWS (BATCH*SEQ)          // 4096
#define EPS 1e-6f

typedef float f32x4  __attribute__((ext_vector_type(4)));
typedef float f32x16 __attribute__((ext_vector_type(16)));
typedef short s16x4  __attribute__((ext_vector_type(4)));
typedef short s16x8  __attribute__((ext_vector_type(8)));

static __device__ __forceinline__ short f2bf(float f) {
    union { float f; unsigned u; } x; x.f = f;
    unsigned r = x.u + 0x7FFFu + ((x.u >> 16) & 1u);
    return (short)(r >> 16);
}
static __device__ __forceinline__ s16x8 pack8(float4 lo, float4 hi) {
    s16x8 r;
    r[0]=f2bf(lo.x); r[1]=f2bf(lo.y); r[2]=f2bf(lo.z); r[3]=f2bf(lo.w);
    r[4]=f2bf(hi.x); r[5]=f2bf(hi.y); r[6]=f2bf(hi.z); r[7]=f2bf(hi.w);
    return r;
}
static __device__ __forceinline__ unsigned cvtpk(float a, float b) {
    unsigned r;
    asm("v_cvt_pk_bf16_f32 %0, %1, %2" : "=v"(r) : "v"(a), "v"(b));
    return r;
}
static __device__ __forceinline__ void gld16(short* l, const short* g) {
    __builtin_amdgcn_global_load_lds(
        (const __attribute__((address_space(1))) void*)g,
        (__attribute__((address_space(3))) void*)l, 16, 0, 0);
}

#define MFMA32(A,B,C) __builtin_amdgcn_mfma_f32_32x32x16_bf16(A, B, C, 0, 0, 0)
#define MFMA16(A,B,C) __builtin_amdgcn_mfma_f32_16x16x32_bf16(A, B, C, 0, 0, 0)

// ---------------------------------------------------------------------------
// fp32 -> bf16 conversion for x, W_qkv, W_proj (one pass, vectorized)
// ---------------------------------------------------------------------------
__global__ __launch_bounds__(256) void convert3(
    const float* __restrict__ x, const float* __restrict__ wq,
    const float* __restrict__ wp,
    short* __restrict__ xb, short* __restrict__ wqb, short* __restrict__ wpb)
{
    const int idx = blockIdx.x * 256 + threadIdx.x;   // one 8-elem chunk
    const int C1 = 4194304/8, C2 = 3145728/8;
    const float* src; short* dst; int off;
    if (idx < C1)            { src = x;  dst = xb;  off = idx; }
    else if (idx < C1 + C2)  { src = wq; dst = wqb; off = idx - C1; }
    else                     { src = wp; dst = wpb; off = idx - C1 - C2; }
    float4 a = ((const float4*)src)[off*2];
    float4 b = ((const float4*)src)[off*2 + 1];
    ((s16x8*)dst)[off] = pack8(a, b);
}

// ---------------------------------------------------------------------------
// bf16 GEMM, m97 structure: 128x128 tile, BK=64, global_load_lds staging.
// MODE 0: fused per-head LayerNorm on q/k, scatter bf16 q/k/v to [B,H,N,D]
// MODE 1: bias add, fp32 out
// ---------------------------------------------------------------------------
#define BKG 64

template<int MODE>
__global__ __launch_bounds__(256) void gemm_bf16(
    const short* __restrict__ A, const short* __restrict__ W,
    const float* __restrict__ bias,
    const float* __restrict__ qg, const float* __restrict__ qbeta,
    const float* __restrict__ kg, const float* __restrict__ kbeta,
    short* __restrict__ qb, short* __restrict__ kb, short* __restrict__ vb,
    float* __restrict__ out)
{
    alignas(16) __shared__ short As[128*BKG];
    alignas(16) __shared__ short Bs[128*BKG];
    const int tid  = threadIdx.x;
    const int lane = tid & 63, wave = tid >> 6;
    const int wr = wave >> 1, wc = wave & 1;
    const int c = lane & 15, g = lane >> 4;
    const int brow = blockIdx.y * 128, bcol = blockIdx.x * 128;

    const int srow = lane >> 3;
    const int scol = (lane & 7) * 8;
    const short* ag = A + (size_t)(brow + srow)*DIM + scol;
    const short* wg = W + (size_t)(bcol + srow)*DIM + scol;

    f32x4 acc[4][4] = {};

    for (int k0 = 0; k0 < DIM; k0 += BKG) {
        #pragma unroll
        for (int j = 0; j < 4; j++) {
            const int rg = (wave*4 + j) * 8;
            gld16(&As[rg*BKG], ag + (size_t)rg*DIM + k0);
            gld16(&Bs[rg*BKG], wg + (size_t)rg*DIM + k0);
        }
        __syncthreads();

        #pragma unroll
        for (int ks = 0; ks < 2; ks++) {
            s16x8 af[4], bf[4];
            #pragma unroll
            for (int m = 0; m < 4; m++)
                af[m] = *(const s16x8*)&As[(wr*64 + m*16 + c)*BKG + ks*32 + g*8];
            #pragma unroll
            for (int n = 0; n < 4; n++)
                bf[n] = *(const s16x8*)&Bs[(wc*64 + n*16 + c)*BKG + ks*32 + g*8];
            #pragma unroll
            for (int m = 0; m < 4; m++)
                #pragma unroll
                for (int n = 0; n < 4; n++)
                    acc[m][n] = MFMA16(af[m], bf[n], acc[m][n]);
        }
        __syncthreads();
    }

    if (MODE == 0) {
        const int colbase = bcol + wc*64;
        const int t = colbase >> 10;               // 0:q 1:k 2:v
        const int h = (colbase >> 6) & 15;
        short* dst = (t == 0) ? qb : (t == 1) ? kb : vb;
        float gam[4], bet[4];
        float scale = 1.0f;
        if (t < 2) {
            const float* G  = (t == 0) ? qg : kg;
            const float* Bt = (t == 0) ? qbeta : kbeta;
            #pragma unroll
            for (int n = 0; n < 4; n++) { gam[n] = G[n*16 + c]; bet[n] = Bt[n*16 + c]; }
            if (t == 0) scale = 0.125f * 1.44269504088896340736f;  // D^-0.5 * log2e
        }
        #pragma unroll
        for (int m = 0; m < 4; m++) {
            #pragma unroll
            for (int j = 0; j < 4; j++) {
                const int row = brow + wr*64 + m*16 + g*4 + j;
                const int bi = row >> 11, ni = row & (SEQ-1);
                const size_t rb = ((size_t)(bi*HEADS + h)*SEQ + ni)*HD;
                float v0 = acc[m][0][j], v1 = acc[m][1][j];
                float v2 = acc[m][2][j], v3 = acc[m][3][j];
                if (t < 2) {
                    float s = (v0 + v1) + (v2 + v3);
                    s += __shfl_xor(s, 1); s += __shfl_xor(s, 2);
                    s += __shfl_xor(s, 4); s += __shfl_xor(s, 8);
                    const float mu = s * 0.015625f;
                    v0 -= mu; v1 -= mu; v2 -= mu; v3 -= mu;
                    float vv = (v0*v0 + v1*v1) + (v2*v2 + v3*v3);
                    vv += __shfl_xor(vv, 1); vv += __shfl_xor(vv, 2);
                    vv += __shfl_xor(vv, 4); vv += __shfl_xor(vv, 8);
                    const float rstd = rsqrtf(vv * 0.015625f + EPS);
                    v0 = (v0*rstd*gam[0] + bet[0]) * scale;
                    v1 = (v1*rstd*gam[1] + bet[1]) * scale;
                    v2 = (v2*rstd*gam[2] + bet[2]) * scale;
                    v3 = (v3*rstd*gam[3] + bet[3]) * scale;
                }
                dst[rb + 0*16 + c] = f2bf(v0);
                dst[rb + 1*16 + c] = f2bf(v1);
                dst[rb + 2*16 + c] = f2bf(v2);
                dst[rb + 3*16 + c] = f2bf(v3);
            }
        }
    } else {
        #pragma unroll
        for (int n = 0; n < 4; n++) {
            const int col = bcol + wc*64 + n*16 + c;
            const float bv = bias[col];
            #pragma unroll
            for (int m = 0; m < 4; m++) {
                #pragma unroll
                for (int j = 0; j < 4; j++) {
                    const int row = brow + wr*64 + m*16 + g*4 + j;
                    out[(size_t)row*DIM + col] = acc[m][n][j] + bv;
                }
            }
        }
    }
}

// ---------------------------------------------------------------------------
// Repack K,V into MFMA-fragment order so attn loads are lane-coalesced:
//  KP[bh][tile32][ks(0..3)][lane][e] = K[bh][tile*32+(lane&31)][ks*16+8*(lane>>5)+e]
//  VP[bh][tile32][idx(0..3)][lane][e] = V[bh][tile*32+(idx>>1)*16+8*(lane>>5)+e][(idx&1)*32+(lane&31)]
// ---------------------------------------------------------------------------
__global__ __launch_bounds__(256) void repack_kv(
    const short* __restrict__ kin, const short* __restrict__ vin,
    short* __restrict__ KP, short* __restrict__ VP)
{
    constexpr int LT = 72;
    alignas(16) __shared__ short Kl[64*LT];
    alignas(16) __shared__ short Vl[64*LT];
    const int bh = blockIdx.x, n0 = blockIdx.y * 64;
    const int tid = threadIdx.x;
    const int r = tid >> 2, cq = (tid & 3) * 16;
    {
        const short* ksrc = kin + ((size_t)bh*SEQ + n0 + r)*HD + cq;
        const short* vsrc = vin + ((size_t)bh*SEQ + n0 + r)*HD + cq;
        *(s16x8*)&Kl[r*LT + cq]     = *(const s16x8*)ksrc;
        *(s16x8*)&Kl[r*LT + cq + 8] = *(const s16x8*)(ksrc + 8);
        *(s16x8*)&Vl[r*LT + cq]     = *(const s16x8*)vsrc;
        *(s16x8*)&Vl[r*LT + cq + 8] = *(const s16x8*)(vsrc + 8);
    }
    __syncthreads();
    const int tt = tid >> 7;              // tile 0/1
    const int r2 = tid & 127;
    const int sub = r2 >> 5, lp = r2 & 31;
    const size_t tbase = ((size_t)bh*64 + blockIdx.y*2 + tt)*2048 + sub*512;
    #pragma unroll
    for (int g2 = 0; g2 < 2; g2++) {
        const int lane = 2*lp + g2;
        s16x8 val = *(const s16x8*)&Kl[(tt*32 + (lane & 31))*LT + sub*16 + 8*(lane >> 5)];
        *(s16x8*)&KP[tbase + lane*8] = val;
    }
    #pragma unroll
    for (int g2 = 0; g2 < 2; g2++) {
        const int lane = 2*lp + g2;
        const int hi = lane >> 5, l31 = lane & 31;
        s16x8 val;
        #pragma unroll
        for (int e = 0; e < 8; e++)
            val[e] = Vl[(tt*32 + (sub >> 1)*16 + 8*hi + e)*LT + (sub & 1)*32 + l31];
        *(s16x8*)&VP[tbase + lane*8] = val;
    }
}

// ---------------------------------------------------------------------------
// Flash attention: round-7 proven structure (2-way split-K, 2 q-subtiles,
// shfl_xor reduces, 2-way LDS merge) + software-pipelined K/V reloads:
// kc reloaded right after S-MFMA, vc right after PV — each load has a full
// softmax+PV (~500+ cyc) of cover before its next use.
// ---------------------------------------------------------------------------
__global__ __launch_bounds__(256) void attn_kernel(
    const short* __restrict__ qbuf, const short* __restrict__ KP,
    const short* __restrict__ VP, short* __restrict__ aout)
{
    alignas(16) __shared__ float OL[2][64][32];   // [qsub][lane][reg]
    __shared__ float ML[2][2][64];                // [qsub][{m,l}][lane]

    const int bh = blockIdx.x, qt = blockIdx.y;
    const int tid = threadIdx.x, wave = tid >> 6, lane = tid & 63;
    const int qsub = wave >> 1, half = wave & 1;
    const int l31 = lane & 31, hi = lane >> 5;
    const int q0 = qt*64 + qsub*32;

    s16x8 qf[4];
    const short* qrow = qbuf + ((size_t)bh*SEQ + q0 + l31)*HD + 8*hi;
    #pragma unroll
    for (int ks = 0; ks < 4; ks++) qf[ks] = *(const s16x8*)(qrow + 16*ks);

    const short* kp = KP + ((size_t)bh*64 + half*32)*2048 + lane*8;
    const short* vp = VP + ((size_t)bh*64 + half*32)*2048 + lane*8;

    // prologue: tile 0 of this wave's K-half
    s16x8 kc0 = *(const s16x8*)(kp);
    s16x8 kc1 = *(const s16x8*)(kp + 512);
    s16x8 kc2 = *(const s16x8*)(kp + 1024);
    s16x8 kc3 = *(const s16x8*)(kp + 1536);
    s16x8 vc0 = *(const s16x8*)(vp);
    s16x8 vc1 = *(const s16x8*)(vp + 512);
    s16x8 vc2 = *(const s16x8*)(vp + 1024);
    s16x8 vc3 = *(const s16x8*)(vp + 1536);

    f32x16 o0 = {}, o1 = {};
    float m = -1e30f, l = 0.f;

    for (int it = 0; it < 32; it++) {
        // S^T = K*Q : lane holds 16 keys for q = q0+l31
        f32x16 s = {};
        __builtin_amdgcn_s_setprio(1);
        s = MFMA32(kc0, qf[0], s);
        s = MFMA32(kc1, qf[1], s);
        s = MFMA32(kc2, qf[2], s);
        s = MFMA32(kc3, qf[3], s);
        __builtin_amdgcn_s_setprio(0);

        // reload kc for next tile NOW (covered by softmax + PV below)
        const int nt = ((it + 1) & 31) * 2048;
        kc0 = *(const s16x8*)(kp + nt);
        kc1 = *(const s16x8*)(kp + nt + 512);
        kc2 = *(const s16x8*)(kp + nt + 1024);
        kc3 = *(const s16x8*)(kp + nt + 1536);
        __builtin_amdgcn_sched_barrier(0);

        // softmax (round-7 exact)
        float t8[8];
        #pragma unroll
        for (int i = 0; i < 8; i++) t8[i] = fmaxf(s[i], s[i+8]);
        #pragma unroll
        for (int i = 0; i < 4; i++) t8[i] = fmaxf(t8[i], t8[i+4]);
        float pmax = fmaxf(fmaxf(t8[0], t8[2]), fmaxf(t8[1], t8[3]));
        pmax = fmaxf(pmax, __shfl_xor(pmax, 32));

        if (!__all(pmax - m <= 8.0f)) {           // defer-max (T13)
            float mn = fmaxf(m, pmax);
            float corr = exp2f(m - mn);
            #pragma unroll
            for (int i = 0; i < 16; i++) { o0[i] *= corr; o1[i] *= corr; }
            l *= corr;
            m = mn;
        }
        #pragma unroll
        for (int i = 0; i < 16; i++) s[i] = exp2f(s[i] - m);
        float a8[8];
        #pragma unroll
        for (int i = 0; i < 8; i++) a8[i] = s[i] + s[i+8];
        #pragma unroll
        for (int i = 0; i < 4; i++) a8[i] += a8[i+4];
        float rs = (a8[0] + a8[2]) + (a8[1] + a8[3]);
        rs += __shfl_xor(rs, 32);
        l += rs;

        // P -> bf16 B-fragments via cvt_pk + permlane32_swap (T12)
        s16x8 pa0, pa1;
        {
            unsigned A0 = cvtpk(s[0], s[1]),  A1 = cvtpk(s[2], s[3]);
            unsigned B0 = cvtpk(s[4], s[5]),  B1 = cvtpk(s[6], s[7]);
            asm volatile("v_permlane32_swap_b32 %0, %1" : "+v"(A0), "+v"(B0));
            asm volatile("v_permlane32_swap_b32 %0, %1" : "+v"(A1), "+v"(B1));
            union { s16x8 v; unsigned u[4]; } w;
            w.u[0]=A0; w.u[1]=A1; w.u[2]=B0; w.u[3]=B1;
            pa0 = w.v;
            unsigned C0 = cvtpk(s[8], s[9]),   C1 = cvtpk(s[10], s[11]);
            unsigned D0 = cvtpk(s[12], s[13]), D1 = cvtpk(s[14], s[15]);
            asm volatile("v_permlane32_swap_b32 %0, %1" : "+v"(C0), "+v"(D0));
            asm volatile("v_permlane32_swap_b32 %0, %1" : "+v"(C1), "+v"(D1));
            union { s16x8 v; unsigned u[4]; } w2;
            w2.u[0]=C0; w2.u[1]=C1; w2.u[2]=D0; w2.u[3]=D1;
            pa1 = w2.v;
        }

        // O^T += V^T * P
        __builtin_amdgcn_s_setprio(1);
        o0 = MFMA32(vc0, pa0, o0);
        o1 = MFMA32(vc1, pa0, o1);
        o0 = MFMA32(vc2, pa1, o0);
        o1 = MFMA32(vc3, pa1, o1);
        __builtin_amdgcn_s_setprio(0);

        // reload vc for next tile (covered by next iter's S phase + softmax)
        vc0 = *(const s16x8*)(vp + nt);
        vc1 = *(const s16x8*)(vp + nt + 512);
        vc2 = *(const s16x8*)(vp + nt + 1024);
        vc3 = *(const s16x8*)(vp + nt + 1536);
    }

    // ---- merge the two K-halves (round-7 exact) ----
    if (half == 1) {
        float* ob = &OL[qsub][lane][0];
        #pragma unroll
        for (int i = 0; i < 8; i++) {
            const int slot = (i + (lane & 7)) & 7;
            f32x4 v;
            if (i < 4) { v[0]=o0[4*i]; v[1]=o0[4*i+1]; v[2]=o0[4*i+2]; v[3]=o0[4*i+3]; }
            else { const int j = i-4; v[0]=o1[4*j]; v[1]=o1[4*j+1]; v[2]=o1[4*j+2]; v[3]=o1[4*j+3]; }
            *(f32x4*)(ob + slot*4) = v;
        }
        ML[qsub][0][lane] = m;
        ML[qsub][1][lane] = l;
    }
    __syncthreads();
    if (half == 0) {
        const float m1 = ML[qsub][0][lane];
        const float l1 = ML[qsub][1][lane];
        const float ms = fmaxf(m, m1);
        const float c0 = exp2f(m - ms), c1 = exp2f(m1 - ms);
        const float inv = 1.0f / (l*c0 + l1*c1);
        const float* ob = &OL[qsub][lane][0];
        const int b = bh >> 4, h = bh & 15;
        short* dst = aout + ((size_t)(b*SEQ + q0 + l31))*DIM + h*HD;
        #pragma unroll
        for (int i = 0; i < 8; i++) {
            const int slot = (i + (lane & 7)) & 7;
            f32x4 p = *(const f32x4*)(ob + slot*4);
            s16x4 st;
            if (i < 4) {
                #pragma unroll
                for (int j = 0; j < 4; j++) st[j] = f2bf((o0[4*i+j]*c0 + p[j]*c1) * inv);
                *(s16x4*)(dst + 8*i + 4*hi) = st;
            } else {
                const int t3 = i - 4;
                #pragma unroll
                for (int j = 0; j < 4; j++) st[j] = f2bf((o1[4*t3+j]*c0 + p[j]*c1) * inv);
                *(s16x4*)(dst + 32 + 8*t3 + 4*hi) = st;
            }
        }
    }
}

// ---------------------------------------------------------------------------
extern "C" void kernel_launch(void* const* d_in, const int* in_sizes, int n_in,
                              void* d_out, int out_size, void* d_ws, size_t ws_size,
                              hipStream_t stream)
{
    const float* x     = (const float*)d_in[0];
    const float* Wqkv  = (const float*)d_in[1];
    const float* qg    = (const float*)d_in[2];
    const float* qbeta = (const float*)d_in[3];
    const float* kg    = (const float*)d_in[4];
    const float* kbeta = (const float*)d_in[5];
    const float* Wproj = (const float*)d_in[6];
    const float* bproj = (const float*)d_in[7];
    float* out = (float*)d_out;

    char* ws = (char*)d_ws;
    const size_t MB = 1024*1024;
    short* xb     = (short*)(ws);              // 8 MB; dead after gemm<0>
    short* KP     = (short*)(ws);              // reuses xb slot (written by repack)
    short* wqkvb  = (short*)(ws + 8*MB);       // 6 MB
    short* wprojb = (short*)(ws + 14*MB);      // 2 MB (live until gemm<1>)
    short* q      = (short*)(ws + 16*MB);      // 8 MB
    short* k      = (short*)(ws + 24*MB);      // 8 MB; dead after repack
    short* aout   = (short*)(ws + 24*MB);      // reuses k slot (written by attn)
    short* vrow   = (short*)(ws + 32*MB);      // 8 MB; dead after repack
    short* VP     = (short*)(ws + 40*MB);      // 8 MB

    // 1. fp32 -> bf16 conversions
    convert3<<<dim3(4096), 256, 0, stream>>>(x, Wqkv, Wproj, xb, wqkvb, wprojb);

    // 2. QKV GEMM + fused q/k LayerNorm, scatter
    gemm_bf16<0><<<dim3(3*DIM/128, ROWS/128), 256, 0, stream>>>(
        xb, wqkvb, nullptr, qg, qbeta, kg, kbeta, q, k, vrow, nullptr);

    // 3. Repack K,V into fragment order
    repack_kv<<<dim3(BATCH*HEADS, SEQ/64), 256, 0, stream>>>(k, vrow, KP, VP);

    // 4. Flash attention (2-way split-K, software-pipelined, bf16 out)
    attn_kernel<<<dim3(BATCH*HEADS, SEQ/64), 256, 0, stream>>>(q, KP, VP, aout);

    // 5. Projection GEMM + bias -> fp32 d_out
    gemm_bf16<1><<<dim3(DIM/128, ROWS/128), 256, 0, stream>>>(
        aout, wprojb, bproj, nullptr, nullptr, nullptr, nullptr,
        nullptr, nullptr, nullptr, out);
}